// Round 7
// baseline (238.889 us; speedup 1.0000x reference)
//
#include <hip/hip_runtime.h>
#include <hip/hip_bf16.h>
#include <math.h>

#define N_ATOM   100000
#define N_QUERY  20000
#define KNN      32

typedef __attribute__((ext_vector_type(8))) short  short8;
typedef __attribute__((ext_vector_type(4))) float  floatx4;
typedef __attribute__((ext_vector_type(2))) float  fx2;

static __device__ __forceinline__ unsigned short f2bf_bits(float f) {
  union { __hip_bfloat16 h; unsigned short u; } cv;
  cv.h = __float2bfloat16(f);
  return cv.u;
}
static __device__ __forceinline__ float bflo(unsigned int u) { return __uint_as_float(u << 16); }
static __device__ __forceinline__ float bfhi(unsigned int u) { return __uint_as_float(u & 0xffff0000u); }

// ---------------- pack ALL weights into MFMA B-fragment order (bf16), one launch ----------------
// dst[((ktile*NT + ntile)*64 + lane)*8 + j] = W^T[ktile*32 + (lane>>4)*8 + j][ntile*16 + (lane&15)]
__global__ void pack_all_kernel(const float* __restrict__ Wq, const float* __restrict__ Wk,
                                const float* __restrict__ Wv, const float* __restrict__ W1,
                                const float* __restrict__ W2,
                                unsigned short* __restrict__ WKVp, unsigned short* __restrict__ WQp,
                                unsigned short* __restrict__ W1p,  unsigned short* __restrict__ W2p) {
  int tid = blockIdx.x * blockDim.x + threadIdx.x;
  if (tid >= 98304) return;
  const float *Wa, *Wb; int nsplit, Kd, Nd; unsigned short* dst; float scale = 1.0f;
  int t = tid;
  if (t < 32768)      { Wa = Wk; Wb = Wv; nsplit = 128; Kd = 128; Nd = 256; dst = WKVp; }
  else if (t < 49152) { t -= 32768; Wa = Wq; Wb = Wq; nsplit = 128; Kd = 128; Nd = 128; dst = WQp; scale = 0.25f; }
  else if (t < 81920) { t -= 49152; Wa = W1; Wb = W1; nsplit = 128; Kd = 256; Nd = 128; dst = W1p; }
  else                { t -= 81920; Wa = W2; Wb = W2; nsplit = 128; Kd = 128; Nd = 128; dst = W2p; }
  int j    = t & 7;
  int lane = (t >> 3) & 63;
  int t2   = t >> 9;
  int NT   = Nd >> 4;
  int ntile = t2 % NT;
  int ktile = t2 / NT;
  int k = ktile * 32 + (lane >> 4) * 8 + j;
  int n = ntile * 16 + (lane & 15);
  float v = (n < nsplit) ? Wa[(size_t)n * Kd + k] : Wb[(size_t)(n - nsplit) * Kd + k];
  dst[t] = f2bf_bits(v * scale);
}

// ---------------- merged KV+Q projection GEMM ----------------
// Blocks [0, KB): KV tile (MT=2 x NT=8 per wave; 2 row-groups x 2 col-groups) -> interleaved
//   fp8 table KVp8[atom][256] (K cols 0..127 | V cols 128..255) via 16 KB LDS, dwordx4 copy-out.
// Blocks [KB, KB+QB): Q tile (MT=1, NT=8) -> bf16 direct store.
__global__ __launch_bounds__(256) void gemm_kvq(
    const float* __restrict__ h_atom, const float* __restrict__ h_query,
    const unsigned short* __restrict__ WKVp, const unsigned short* __restrict__ WQp,
    unsigned char* __restrict__ KVp8, unsigned short* __restrict__ Qb) {
  constexpr int KB = (N_ATOM + 63) / 64;
  __shared__ char lds[16384];
  const int l    = threadIdx.x & 63;
  const int w    = threadIdx.x >> 6;
  const int quad = l >> 4;
  const int col0 = l & 15;

  if ((int)blockIdx.x < KB) {
    const int rg = w >> 1;            // row-group (32 rows each)
    const int cg = w & 1;             // col-group (128 cols each)
    const int rowb = blockIdx.x * 64;
    int arow[2];
#pragma unroll
    for (int mt = 0; mt < 2; mt++) {
      int r = rowb + rg * 32 + mt * 16 + col0;
      arow[mt] = (r < N_ATOM) ? r : (N_ATOM - 1);
    }
    floatx4 acc[2][8];
#pragma unroll
    for (int mt = 0; mt < 2; mt++)
#pragma unroll
      for (int nt = 0; nt < 8; nt++) acc[mt][nt] = (floatx4){0.f, 0.f, 0.f, 0.f};

#pragma unroll
    for (int k0 = 0; k0 < 128; k0 += 32) {
      short8 af[2];
#pragma unroll
      for (int mt = 0; mt < 2; mt++) {
        const float* ap = h_atom + (size_t)arow[mt] * 128 + k0 + quad * 8;
        floatx4 a0 = *(const floatx4*)(ap);
        floatx4 a1 = *(const floatx4*)(ap + 4);
        af[mt][0] = (short)f2bf_bits(a0[0]); af[mt][1] = (short)f2bf_bits(a0[1]);
        af[mt][2] = (short)f2bf_bits(a0[2]); af[mt][3] = (short)f2bf_bits(a0[3]);
        af[mt][4] = (short)f2bf_bits(a1[0]); af[mt][5] = (short)f2bf_bits(a1[1]);
        af[mt][6] = (short)f2bf_bits(a1[2]); af[mt][7] = (short)f2bf_bits(a1[3]);
      }
      const unsigned short* bbase = WKVp + ((size_t)(k0 >> 5) * 16 + cg * 8) * 512 + l * 8;
#pragma unroll
      for (int nt = 0; nt < 8; nt++) {
        short8 bf = *(const short8*)(bbase + nt * 512);
#pragma unroll
        for (int mt = 0; mt < 2; mt++)
          acc[mt][nt] = __builtin_amdgcn_mfma_f32_16x16x32_bf16(af[mt], bf, acc[mt][nt], 0, 0, 0);
      }
    }
    // stage fp8 into interleaved LDS tile [64][256]
#pragma unroll
    for (int mt = 0; mt < 2; mt++) {
#pragma unroll
      for (int nt = 0; nt < 8; nt++) {
#pragma unroll
        for (int r = 0; r < 4; r++) {
          int rl = rg * 32 + mt * 16 + quad * 4 + r;  // local row
          int c  = cg * 128 + nt * 16 + col0;         // 0..255 (K|V interleaved)
          int pk = __builtin_amdgcn_cvt_pk_fp8_f32(acc[mt][nt][r], acc[mt][nt][r], 0, false);
          lds[rl * 256 + c] = (char)(pk & 0xff);
        }
      }
    }
    __syncthreads();
#pragma unroll
    for (int it = 0; it < 4; it++) {
      int off = threadIdx.x * 16 + it * 4096;
      if (rowb + (off >> 8) < N_ATOM)
        *(float4*)(KVp8 + (size_t)rowb * 256 + off) = *(const float4*)&lds[off];
    }
  } else {
    const int row0 = ((int)blockIdx.x - KB) * 64 + w * 16;
    int arow = row0 + col0;
    if (arow >= N_QUERY) arow = N_QUERY - 1;
    floatx4 acc[8];
#pragma unroll
    for (int i = 0; i < 8; i++) acc[i] = (floatx4){0.f, 0.f, 0.f, 0.f};
    const float* aptr = h_query + (size_t)arow * 128 + quad * 8;
#pragma unroll
    for (int k0 = 0; k0 < 128; k0 += 32) {
      floatx4 a0 = *(const floatx4*)(aptr + k0);
      floatx4 a1 = *(const floatx4*)(aptr + k0 + 4);
      short8 af;
      af[0] = (short)f2bf_bits(a0[0]); af[1] = (short)f2bf_bits(a0[1]);
      af[2] = (short)f2bf_bits(a0[2]); af[3] = (short)f2bf_bits(a0[3]);
      af[4] = (short)f2bf_bits(a1[0]); af[5] = (short)f2bf_bits(a1[1]);
      af[6] = (short)f2bf_bits(a1[2]); af[7] = (short)f2bf_bits(a1[3]);
      const unsigned short* bbase = WQp + (size_t)(k0 >> 5) * 8 * 512 + l * 8;
#pragma unroll
      for (int nt = 0; nt < 8; nt++) {
        short8 bf = *(const short8*)(bbase + nt * 512);
        acc[nt] = __builtin_amdgcn_mfma_f32_16x16x32_bf16(af, bf, acc[nt], 0, 0, 0);
      }
    }
#pragma unroll
    for (int nt = 0; nt < 8; nt++) {
#pragma unroll
      for (int r = 0; r < 4; r++) {
        int row = row0 + quad * 4 + r;    // C/D: row = (lane>>4)*4 + reg, col = lane&15
        if (row < N_QUERY) Qb[(size_t)row * 128 + nt * 16 + col0] = f2bf_bits(acc[nt][r]);
      }
    }
  }
}

// ---------------- attention: lane owns (edge-slot, head); interleaved fp8 KV gather -------------
// Wave per query. Lane l: j = l>>3 (edge slot), h = l&7 (head). 4 passes of 8 edges.
// src values preloaded directly (L1 broadcast over h-lanes) — no DS op in the address chain.
// Softmax is shift-invariant and scores are O(10) -> no max pass needed.
__global__ __launch_bounds__(256) void attn_kernel(
    const unsigned short* __restrict__ Qb,    // [N_QUERY][128] bf16 (pre-scaled 1/sqrt(16))
    const unsigned char* __restrict__ KVp8,   // [N_ATOM][256] fp8 e4m3 (K | V)
    const float* __restrict__ edge_attr,      // [E][16]
    const float* __restrict__ Wrbf,           // [8][16]
    const int* __restrict__ src,              // [E]
    float* __restrict__ Agg) {                // [N_QUERY][128]
  const int l = threadIdx.x & 63;
  const int w = threadIdx.x >> 6;
  const int q = blockIdx.x * 4 + w;
  const int j = l >> 3;
  const int h = l & 7;

  const int e0 = q * KNN;
  int s_arr[4];
#pragma unroll
  for (int p = 0; p < 4; p++) s_arr[p] = src[e0 + p * 8 + j];

  float qd[16];
  {
    const unsigned int* qp = (const unsigned int*)(Qb + (size_t)q * 128 + h * 16);
#pragma unroll
    for (int i = 0; i < 8; i++) {
      unsigned int u = qp[i];
      qd[2 * i] = bflo(u); qd[2 * i + 1] = bfhi(u);
    }
  }
  float wr[16];
  {
    const float* wp = Wrbf + h * 16;
#pragma unroll
    for (int i = 0; i < 16; i++) wr[i] = wp[i];
  }

  float acc[16];
#pragma unroll
  for (int i = 0; i < 16; i++) acc[i] = 0.f;
  float lsum = 0.f;

#pragma unroll
  for (int p = 0; p < 4; p++) {
    const int e = p * 8 + j;
    const unsigned char* bp = KVp8 + (size_t)s_arr[p] * 256;
    uint4 kq = *(const uint4*)(bp + h * 16);          // 16 fp8 K dims
    uint4 vq = *(const uint4*)(bp + 128 + h * 16);    // 16 fp8 V dims
    const float4* ep = (const float4*)(edge_attr + (size_t)(e0 + e) * 16);
    float4 ea0 = ep[0], ea1 = ep[1], ea2 = ep[2], ea3 = ep[3];

    float kd = 0.f;
    {
      fx2 f0, f1;
      f0 = __builtin_amdgcn_cvt_pk_f32_fp8((int)kq.x, false);
      f1 = __builtin_amdgcn_cvt_pk_f32_fp8((int)kq.x, true);
      kd += qd[0] * f0[0] + qd[1] * f0[1] + qd[2] * f1[0] + qd[3] * f1[1];
      f0 = __builtin_amdgcn_cvt_pk_f32_fp8((int)kq.y, false);
      f1 = __builtin_amdgcn_cvt_pk_f32_fp8((int)kq.y, true);
      kd += qd[4] * f0[0] + qd[5] * f0[1] + qd[6] * f1[0] + qd[7] * f1[1];
      f0 = __builtin_amdgcn_cvt_pk_f32_fp8((int)kq.z, false);
      f1 = __builtin_amdgcn_cvt_pk_f32_fp8((int)kq.z, true);
      kd += qd[8] * f0[0] + qd[9] * f0[1] + qd[10] * f1[0] + qd[11] * f1[1];
      f0 = __builtin_amdgcn_cvt_pk_f32_fp8((int)kq.w, false);
      f1 = __builtin_amdgcn_cvt_pk_f32_fp8((int)kq.w, true);
      kd += qd[12] * f0[0] + qd[13] * f0[1] + qd[14] * f1[0] + qd[15] * f1[1];
    }
    float ed = wr[0]*ea0.x + wr[1]*ea0.y + wr[2]*ea0.z + wr[3]*ea0.w
             + wr[4]*ea1.x + wr[5]*ea1.y + wr[6]*ea1.z + wr[7]*ea1.w
             + wr[8]*ea2.x + wr[9]*ea2.y + wr[10]*ea2.z + wr[11]*ea2.w
             + wr[12]*ea3.x + wr[13]*ea3.y + wr[14]*ea3.z + wr[15]*ea3.w;

    float pe = __expf(kd + ed);
    lsum += pe;
    {
      fx2 g0, g1;
      g0 = __builtin_amdgcn_cvt_pk_f32_fp8((int)vq.x, false);
      g1 = __builtin_amdgcn_cvt_pk_f32_fp8((int)vq.x, true);
      acc[0] += pe * g0[0]; acc[1] += pe * g0[1]; acc[2] += pe * g1[0]; acc[3] += pe * g1[1];
      g0 = __builtin_amdgcn_cvt_pk_f32_fp8((int)vq.y, false);
      g1 = __builtin_amdgcn_cvt_pk_f32_fp8((int)vq.y, true);
      acc[4] += pe * g0[0]; acc[5] += pe * g0[1]; acc[6] += pe * g1[0]; acc[7] += pe * g1[1];
      g0 = __builtin_amdgcn_cvt_pk_f32_fp8((int)vq.z, false);
      g1 = __builtin_amdgcn_cvt_pk_f32_fp8((int)vq.z, true);
      acc[8] += pe * g0[0]; acc[9] += pe * g0[1]; acc[10] += pe * g1[0]; acc[11] += pe * g1[1];
      g0 = __builtin_amdgcn_cvt_pk_f32_fp8((int)vq.w, false);
      g1 = __builtin_amdgcn_cvt_pk_f32_fp8((int)vq.w, true);
      acc[12] += pe * g0[0]; acc[13] += pe * g0[1]; acc[14] += pe * g1[0]; acc[15] += pe * g1[1];
    }
  }

#pragma unroll
  for (int mask = 8; mask <= 32; mask <<= 1) {
    lsum += __shfl_xor(lsum, mask, 64);
#pragma unroll
    for (int i = 0; i < 16; i++) acc[i] += __shfl_xor(acc[i], mask, 64);
  }
  float inv = 1.f / (lsum + 1e-16f);
  float* dst = Agg + (size_t)q * 128 + h * 16;
  if (j == 0) {
    float4 o0 = {acc[0] * inv, acc[1] * inv, acc[2] * inv, acc[3] * inv};
    float4 o1 = {acc[4] * inv, acc[5] * inv, acc[6] * inv, acc[7] * inv};
    *(float4*)(dst)     = o0;
    *(float4*)(dst + 4) = o1;
  } else if (j == 1) {
    float4 o2 = {acc[8] * inv, acc[9] * inv, acc[10] * inv, acc[11] * inv};
    float4 o3 = {acc[12] * inv, acc[13] * inv, acc[14] * inv, acc[15] * inv};
    *(float4*)(dst + 8)  = o2;
    *(float4*)(dst + 12) = o3;
  }
}

// ---------------- fused MLP: relu([h_query|Agg]@W1^T+b1) @ W2^T + b2 + resid -> LayerNorm -------
__global__ __launch_bounds__(256) void mlp_kernel(
    const float* __restrict__ h_query, const float* __restrict__ Agg,
    const unsigned short* __restrict__ W1p, const unsigned short* __restrict__ W2p,
    const float* __restrict__ b1, const float* __restrict__ b2,
    const float* __restrict__ gamma, const float* __restrict__ beta,
    float* __restrict__ out) {
  constexpr int M = N_QUERY;
  constexpr int STRIDE = 136;               // ushorts per LDS row (272 B)
  __shared__ unsigned short hid[64 * STRIDE];

  const int l    = threadIdx.x & 63;
  const int w    = threadIdx.x >> 6;
  const int quad = l >> 4;
  const int col0 = l & 15;
  const int row0 = blockIdx.x * 64 + w * 16;
  int arow = row0 + col0;
  if (arow >= M) arow = M - 1;

  floatx4 acc[8];
#pragma unroll
  for (int i = 0; i < 8; i++) acc[i] = (floatx4){0.f, 0.f, 0.f, 0.f};
#pragma unroll
  for (int k0 = 0; k0 < 256; k0 += 32) {
    const float* sp = (k0 < 128) ? (h_query + (size_t)arow * 128 + k0)
                                 : (Agg + (size_t)arow * 128 + (k0 - 128));
    floatx4 a0 = *(const floatx4*)(sp + quad * 8);
    floatx4 a1 = *(const floatx4*)(sp + quad * 8 + 4);
    short8 af;
    af[0] = (short)f2bf_bits(a0[0]); af[1] = (short)f2bf_bits(a0[1]);
    af[2] = (short)f2bf_bits(a0[2]); af[3] = (short)f2bf_bits(a0[3]);
    af[4] = (short)f2bf_bits(a1[0]); af[5] = (short)f2bf_bits(a1[1]);
    af[6] = (short)f2bf_bits(a1[2]); af[7] = (short)f2bf_bits(a1[3]);
    const unsigned short* bbase = W1p + (size_t)(k0 >> 5) * 8 * 512 + l * 8;
#pragma unroll
    for (int nt = 0; nt < 8; nt++) {
      short8 bf = *(const short8*)(bbase + nt * 512);
      acc[nt] = __builtin_amdgcn_mfma_f32_16x16x32_bf16(af, bf, acc[nt], 0, 0, 0);
    }
  }
#pragma unroll
  for (int nt = 0; nt < 8; nt++) {
#pragma unroll
    for (int r = 0; r < 4; r++) {
      int rl = w * 16 + quad * 4 + r;
      float v = acc[nt][r] + b1[nt * 16 + col0];
      hid[rl * STRIDE + nt * 16 + col0] = f2bf_bits(fmaxf(v, 0.f));
    }
  }
  __syncthreads();

  floatx4 acc2[8];
#pragma unroll
  for (int i = 0; i < 8; i++) acc2[i] = (floatx4){0.f, 0.f, 0.f, 0.f};
  const int rloc = w * 16 + col0;
#pragma unroll
  for (int k0 = 0; k0 < 128; k0 += 32) {
    short8 af = *(const short8*)(hid + rloc * STRIDE + k0 + quad * 8);
    const unsigned short* bbase = W2p + (size_t)(k0 >> 5) * 8 * 512 + l * 8;
#pragma unroll
    for (int nt = 0; nt < 8; nt++) {
      short8 bf = *(const short8*)(bbase + nt * 512);
      acc2[nt] = __builtin_amdgcn_mfma_f32_16x16x32_bf16(af, bf, acc2[nt], 0, 0, 0);
    }
  }

#pragma unroll
  for (int r = 0; r < 4; r++) {
    int row = row0 + quad * 4 + r;
    int rr  = row < M ? row : M - 1;
    float v[8];
    float s1 = 0.f, s2 = 0.f;
#pragma unroll
    for (int nt = 0; nt < 8; nt++) {
      int c = nt * 16 + col0;
      v[nt] = acc2[nt][r] + b2[c] + h_query[(size_t)rr * 128 + c];
      s1 += v[nt];
    }
    s1 += __shfl_xor(s1, 1, 64); s1 += __shfl_xor(s1, 2, 64);
    s1 += __shfl_xor(s1, 4, 64); s1 += __shfl_xor(s1, 8, 64);
#pragma unroll
    for (int nt = 0; nt < 8; nt++) s2 += v[nt] * v[nt];
    s2 += __shfl_xor(s2, 1, 64); s2 += __shfl_xor(s2, 2, 64);
    s2 += __shfl_xor(s2, 4, 64); s2 += __shfl_xor(s2, 8, 64);
    float mean = s1 * (1.0f / 128.0f);
    float var  = s2 * (1.0f / 128.0f) - mean * mean;
    float rstd = rsqrtf(var + 1e-5f);
    if (row < M) {
#pragma unroll
      for (int nt = 0; nt < 8; nt++) {
        int c = nt * 16 + col0;
        out[(size_t)row * 128 + c] = (v[nt] - mean) * rstd * gamma[c] + beta[c];
      }
    }
  }
}

extern "C" void kernel_launch(void* const* d_in, const int* in_sizes, int n_in,
                              void* d_out, int out_size, void* d_ws, size_t ws_size,
                              hipStream_t stream) {
  const float* h_atom    = (const float*)d_in[0];
  const float* h_query   = (const float*)d_in[1];
  const float* edge_attr = (const float*)d_in[2];
  const float* W_q  = (const float*)d_in[3];
  const float* W_k  = (const float*)d_in[4];
  const float* W_v  = (const float*)d_in[5];
  const float* Wrbf = (const float*)d_in[6];
  const float* W1   = (const float*)d_in[7];
  const float* b1   = (const float*)d_in[8];
  const float* W2   = (const float*)d_in[9];
  const float* b2   = (const float*)d_in[10];
  const float* ln_g = (const float*)d_in[11];
  const float* ln_b = (const float*)d_in[12];
  const int* edge_index = (const int*)d_in[13];   // [0..E) = src
  float* out = (float*)d_out;

  char* ws = (char*)d_ws;
  unsigned char*  KVp8 = (unsigned char*)(ws);                 // 100000*256 B = 25.6 MB
  unsigned short* Qb   = (unsigned short*)(ws + 25600000);     // 20000*128 bf16 = 5.12 MB
  float* Agg           = (float*)(ws + 30720000);              // 20000*128 f32  = 10.24 MB
  unsigned short* WKVp = (unsigned short*)(ws + 40960000);     // 128x256
  unsigned short* WQp  = WKVp + 32768;                         // 128x128
  unsigned short* W1p  = WQp  + 16384;                         // 256x128
  unsigned short* W2p  = W1p  + 32768;                         // 128x128

  pack_all_kernel<<<(98304 + 255) / 256, 256, 0, stream>>>(
      W_q, W_k, W_v, W1, W2, WKVp, WQp, W1p, W2p);

  // merged: KV(fp8, interleaved) = h_atom @ [W_k|W_v]^T  and  Q(bf16) = h_query @ (W_q/4)^T
  constexpr int KB = (N_ATOM + 63) / 64;
  constexpr int QB = (N_QUERY + 63) / 64;
  gemm_kvq<<<KB + QB, 256, 0, stream>>>(h_atom, h_query, WKVp, WQp, KVp8, Qb);

  // attention -> Agg
  attn_kernel<<<N_QUERY / 4, 256, 0, stream>>>(Qb, KVp8, edge_attr, Wrbf, edge_index, Agg);

  // fused MLP + residual + LayerNorm -> out
  mlp_kernel<<<(N_QUERY + 63) / 64, 256, 0, stream>>>(
      h_query, Agg, W1p, W2p, b1, b2, ln_g, ln_b, out);
}

// Round 8
// 217.580 us; speedup vs baseline: 1.0979x; 1.0979x over previous
//
#include <hip/hip_runtime.h>
#include <hip/hip_bf16.h>
#include <math.h>

#define N_ATOM   100000
#define N_QUERY  20000
#define KNN      32

typedef __attribute__((ext_vector_type(8))) short  short8;
typedef __attribute__((ext_vector_type(4))) float  floatx4;
typedef __attribute__((ext_vector_type(2))) float  fx2;

static __device__ __forceinline__ unsigned short f2bf_bits(float f) {
  union { __hip_bfloat16 h; unsigned short u; } cv;
  cv.h = __float2bfloat16(f);
  return cv.u;
}
static __device__ __forceinline__ float bflo(unsigned int u) { return __uint_as_float(u << 16); }
static __device__ __forceinline__ float bfhi(unsigned int u) { return __uint_as_float(u & 0xffff0000u); }

// ---------------- pack ALL weights into MFMA B-fragment order (bf16), one launch ----------------
// dst[((ktile*NT + ntile)*64 + lane)*8 + j] = W^T[ktile*32 + (lane>>4)*8 + j][ntile*16 + (lane&15)]
__global__ void pack_all_kernel(const float* __restrict__ Wq, const float* __restrict__ Wk,
                                const float* __restrict__ Wv, const float* __restrict__ W1,
                                const float* __restrict__ W2,
                                unsigned short* __restrict__ WKVp, unsigned short* __restrict__ WQp,
                                unsigned short* __restrict__ W1p,  unsigned short* __restrict__ W2p) {
  int tid = blockIdx.x * blockDim.x + threadIdx.x;
  if (tid >= 98304) return;
  const float *Wa, *Wb; int nsplit, Kd, Nd; unsigned short* dst; float scale = 1.0f;
  int t = tid;
  if (t < 32768)      { Wa = Wk; Wb = Wv; nsplit = 128; Kd = 128; Nd = 256; dst = WKVp; }
  else if (t < 49152) { t -= 32768; Wa = Wq; Wb = Wq; nsplit = 128; Kd = 128; Nd = 128; dst = WQp; scale = 0.25f; }
  else if (t < 81920) { t -= 49152; Wa = W1; Wb = W1; nsplit = 128; Kd = 256; Nd = 128; dst = W1p; }
  else                { t -= 81920; Wa = W2; Wb = W2; nsplit = 128; Kd = 128; Nd = 128; dst = W2p; }
  int j    = t & 7;
  int lane = (t >> 3) & 63;
  int t2   = t >> 9;
  int NT   = Nd >> 4;
  int ntile = t2 % NT;
  int ktile = t2 / NT;
  int k = ktile * 32 + (lane >> 4) * 8 + j;
  int n = ntile * 16 + (lane & 15);
  float v = (n < nsplit) ? Wa[(size_t)n * Kd + k] : Wb[(size_t)(n - nsplit) * Kd + k];
  dst[t] = f2bf_bits(v * scale);
}

// ---------------- merged KV+Q projection GEMM (MT=1, NT=16 KV / NT=8 Q) ----------------
// Blocks [0, KB): KV tile — K,V both fp8 e4m3 via 16 KB LDS -> coalesced dwordx4 copy-out.
//   A-row (512 B) fully prefetched before the MFMA loop: 8 long-latency loads in flight.
// Blocks [KB, KB+QB): Q tile — bf16 direct store.
__global__ __launch_bounds__(256) void gemm_kvq(
    const float* __restrict__ h_atom, const float* __restrict__ h_query,
    const unsigned short* __restrict__ WKVp, const unsigned short* __restrict__ WQp,
    unsigned char* __restrict__ Kp8, unsigned char* __restrict__ Vp8,
    unsigned short* __restrict__ Qb) {
  constexpr int KB = (N_ATOM + 63) / 64;
  __shared__ char lds[16384];
  const int l    = threadIdx.x & 63;
  const int w    = threadIdx.x >> 6;
  const int quad = l >> 4;
  const int col0 = l & 15;

  if ((int)blockIdx.x < KB) {
    const int row0 = blockIdx.x * 64 + w * 16;
    int arow = row0 + col0;
    if (arow >= N_ATOM) arow = N_ATOM - 1;

    // prefetch the whole A-row slice for this lane: 4 k-iters x 2 float4
    const float* aptr = h_atom + (size_t)arow * 128 + quad * 8;
    floatx4 a[8];
#pragma unroll
    for (int k0 = 0; k0 < 4; k0++) {
      a[2 * k0]     = *(const floatx4*)(aptr + k0 * 32);
      a[2 * k0 + 1] = *(const floatx4*)(aptr + k0 * 32 + 4);
    }
    short8 af[4];
#pragma unroll
    for (int k0 = 0; k0 < 4; k0++) {
      af[k0][0] = (short)f2bf_bits(a[2*k0][0]); af[k0][1] = (short)f2bf_bits(a[2*k0][1]);
      af[k0][2] = (short)f2bf_bits(a[2*k0][2]); af[k0][3] = (short)f2bf_bits(a[2*k0][3]);
      af[k0][4] = (short)f2bf_bits(a[2*k0+1][0]); af[k0][5] = (short)f2bf_bits(a[2*k0+1][1]);
      af[k0][6] = (short)f2bf_bits(a[2*k0+1][2]); af[k0][7] = (short)f2bf_bits(a[2*k0+1][3]);
    }

    floatx4 acc[16];
#pragma unroll
    for (int i = 0; i < 16; i++) acc[i] = (floatx4){0.f, 0.f, 0.f, 0.f};
#pragma unroll
    for (int k0 = 0; k0 < 4; k0++) {
      const unsigned short* bbase = WKVp + (size_t)k0 * 16 * 512 + l * 8;
#pragma unroll
      for (int nt = 0; nt < 16; nt++) {
        short8 bf = *(const short8*)(bbase + nt * 512);
        acc[nt] = __builtin_amdgcn_mfma_f32_16x16x32_bf16(af[k0], bf, acc[nt], 0, 0, 0);
      }
    }
    // stage both halves as fp8 into LDS: K tile 64x128B at 0, V tile 64x128B at 8192
#pragma unroll
    for (int nt = 0; nt < 16; nt++) {
#pragma unroll
      for (int r = 0; r < 4; r++) {
        int rl = w * 16 + quad * 4 + r;   // local row
        int c  = nt * 16 + col0;
        int pk = __builtin_amdgcn_cvt_pk_fp8_f32(acc[nt][r], acc[nt][r], 0, false);
        if (c < 128) lds[rl * 128 + c] = (char)(pk & 0xff);
        else         lds[8192 + rl * 128 + (c - 128)] = (char)(pk & 0xff);
      }
    }
    __syncthreads();
    const int row0g = blockIdx.x * 64;
#pragma unroll
    for (int it = 0; it < 2; it++) {
      int off = threadIdx.x * 16 + it * 4096;
      if (row0g + (off >> 7) < N_ATOM)
        *(float4*)(Kp8 + (size_t)row0g * 128 + off) = *(const float4*)&lds[off];
    }
#pragma unroll
    for (int it = 0; it < 2; it++) {
      int off = threadIdx.x * 16 + it * 4096;
      if (row0g + (off >> 7) < N_ATOM)
        *(float4*)(Vp8 + (size_t)row0g * 128 + off) = *(const float4*)&lds[8192 + off];
    }
  } else {
    const int row0 = ((int)blockIdx.x - KB) * 64 + w * 16;
    int arow = row0 + col0;
    if (arow >= N_QUERY) arow = N_QUERY - 1;
    floatx4 acc[8];
#pragma unroll
    for (int i = 0; i < 8; i++) acc[i] = (floatx4){0.f, 0.f, 0.f, 0.f};
    const float* aptr = h_query + (size_t)arow * 128 + quad * 8;
#pragma unroll
    for (int k0 = 0; k0 < 128; k0 += 32) {
      floatx4 a0 = *(const floatx4*)(aptr + k0);
      floatx4 a1 = *(const floatx4*)(aptr + k0 + 4);
      short8 af;
      af[0] = (short)f2bf_bits(a0[0]); af[1] = (short)f2bf_bits(a0[1]);
      af[2] = (short)f2bf_bits(a0[2]); af[3] = (short)f2bf_bits(a0[3]);
      af[4] = (short)f2bf_bits(a1[0]); af[5] = (short)f2bf_bits(a1[1]);
      af[6] = (short)f2bf_bits(a1[2]); af[7] = (short)f2bf_bits(a1[3]);
      const unsigned short* bbase = WQp + (size_t)(k0 >> 5) * 8 * 512 + l * 8;
#pragma unroll
      for (int nt = 0; nt < 8; nt++) {
        short8 bf = *(const short8*)(bbase + nt * 512);
        acc[nt] = __builtin_amdgcn_mfma_f32_16x16x32_bf16(af, bf, acc[nt], 0, 0, 0);
      }
    }
#pragma unroll
    for (int nt = 0; nt < 8; nt++) {
#pragma unroll
      for (int r = 0; r < 4; r++) {
        int row = row0 + quad * 4 + r;    // C/D: row = (lane>>4)*4 + reg, col = lane&15
        if (row < N_QUERY) Qb[(size_t)row * 128 + nt * 16 + col0] = f2bf_bits(acc[nt][r]);
      }
    }
  }
}

// ---------------- attention: lane owns (edge-slot, head); fp8 K AND V gather ----------------
// (R6 configuration — measured 43.4 us.)  Wave per query. Lane l: j = l>>3, h = l&7.
// 4 passes of 8 edges; score/exp/PV lane-local; single butterfly reduce over j at the end.
// Softmax is shift-invariant and scores are O(10) -> no max pass needed.
__global__ __launch_bounds__(256) void attn_kernel(
    const unsigned short* __restrict__ Qb,    // [N_QUERY][128] bf16 (pre-scaled 1/sqrt(16))
    const unsigned char* __restrict__ Kp8,    // [N_ATOM][128] fp8 e4m3
    const unsigned char* __restrict__ Vp8,    // [N_ATOM][128] fp8 e4m3
    const float* __restrict__ edge_attr,      // [E][16]
    const float* __restrict__ Wrbf,           // [8][16]
    const int* __restrict__ src,              // [E]
    float* __restrict__ Agg) {                // [N_QUERY][128]
  const int l = threadIdx.x & 63;
  const int w = threadIdx.x >> 6;
  const int q = blockIdx.x * 4 + w;
  const int j = l >> 3;
  const int h = l & 7;

  const int e0 = q * KNN;
  int srcj = (l < KNN) ? src[e0 + l] : 0;

  float qd[16];
  {
    const unsigned int* qp = (const unsigned int*)(Qb + (size_t)q * 128 + h * 16);
#pragma unroll
    for (int i = 0; i < 8; i++) {
      unsigned int u = qp[i];
      qd[2 * i] = bflo(u); qd[2 * i + 1] = bfhi(u);
    }
  }
  float wr[16];
  {
    const float* wp = Wrbf + h * 16;
#pragma unroll
    for (int i = 0; i < 16; i++) wr[i] = wp[i];
  }

  float acc[16];
#pragma unroll
  for (int i = 0; i < 16; i++) acc[i] = 0.f;
  float lsum = 0.f;

#pragma unroll
  for (int p = 0; p < 4; p++) {
    const int e = p * 8 + j;
    int s = __shfl(srcj, e, 64);
    uint4 kq = *(const uint4*)(Kp8 + (size_t)s * 128 + h * 16);   // 16 fp8 K dims
    uint4 vq = *(const uint4*)(Vp8 + (size_t)s * 128 + h * 16);   // 16 fp8 V dims
    const float4* ep = (const float4*)(edge_attr + (size_t)(e0 + e) * 16);
    float4 ea0 = ep[0], ea1 = ep[1], ea2 = ep[2], ea3 = ep[3];

    float kd = 0.f;
    {
      fx2 f0, f1;
      f0 = __builtin_amdgcn_cvt_pk_f32_fp8((int)kq.x, false);
      f1 = __builtin_amdgcn_cvt_pk_f32_fp8((int)kq.x, true);
      kd += qd[0] * f0[0] + qd[1] * f0[1] + qd[2] * f1[0] + qd[3] * f1[1];
      f0 = __builtin_amdgcn_cvt_pk_f32_fp8((int)kq.y, false);
      f1 = __builtin_amdgcn_cvt_pk_f32_fp8((int)kq.y, true);
      kd += qd[4] * f0[0] + qd[5] * f0[1] + qd[6] * f1[0] + qd[7] * f1[1];
      f0 = __builtin_amdgcn_cvt_pk_f32_fp8((int)kq.z, false);
      f1 = __builtin_amdgcn_cvt_pk_f32_fp8((int)kq.z, true);
      kd += qd[8] * f0[0] + qd[9] * f0[1] + qd[10] * f1[0] + qd[11] * f1[1];
      f0 = __builtin_amdgcn_cvt_pk_f32_fp8((int)kq.w, false);
      f1 = __builtin_amdgcn_cvt_pk_f32_fp8((int)kq.w, true);
      kd += qd[12] * f0[0] + qd[13] * f0[1] + qd[14] * f1[0] + qd[15] * f1[1];
    }
    float ed = wr[0]*ea0.x + wr[1]*ea0.y + wr[2]*ea0.z + wr[3]*ea0.w
             + wr[4]*ea1.x + wr[5]*ea1.y + wr[6]*ea1.z + wr[7]*ea1.w
             + wr[8]*ea2.x + wr[9]*ea2.y + wr[10]*ea2.z + wr[11]*ea2.w
             + wr[12]*ea3.x + wr[13]*ea3.y + wr[14]*ea3.z + wr[15]*ea3.w;

    float pe = __expf(kd + ed);
    lsum += pe;
    {
      fx2 g0, g1;
      g0 = __builtin_amdgcn_cvt_pk_f32_fp8((int)vq.x, false);
      g1 = __builtin_amdgcn_cvt_pk_f32_fp8((int)vq.x, true);
      acc[0] += pe * g0[0]; acc[1] += pe * g0[1]; acc[2] += pe * g1[0]; acc[3] += pe * g1[1];
      g0 = __builtin_amdgcn_cvt_pk_f32_fp8((int)vq.y, false);
      g1 = __builtin_amdgcn_cvt_pk_f32_fp8((int)vq.y, true);
      acc[4] += pe * g0[0]; acc[5] += pe * g0[1]; acc[6] += pe * g1[0]; acc[7] += pe * g1[1];
      g0 = __builtin_amdgcn_cvt_pk_f32_fp8((int)vq.z, false);
      g1 = __builtin_amdgcn_cvt_pk_f32_fp8((int)vq.z, true);
      acc[8] += pe * g0[0]; acc[9] += pe * g0[1]; acc[10] += pe * g1[0]; acc[11] += pe * g1[1];
      g0 = __builtin_amdgcn_cvt_pk_f32_fp8((int)vq.w, false);
      g1 = __builtin_amdgcn_cvt_pk_f32_fp8((int)vq.w, true);
      acc[12] += pe * g0[0]; acc[13] += pe * g0[1]; acc[14] += pe * g1[0]; acc[15] += pe * g1[1];
    }
  }

#pragma unroll
  for (int mask = 8; mask <= 32; mask <<= 1) {
    lsum += __shfl_xor(lsum, mask, 64);
#pragma unroll
    for (int i = 0; i < 16; i++) acc[i] += __shfl_xor(acc[i], mask, 64);
  }
  float inv = 1.f / (lsum + 1e-16f);
  float* dst = Agg + (size_t)q * 128 + h * 16;
  if (j == 0) {
    float4 o0 = {acc[0] * inv, acc[1] * inv, acc[2] * inv, acc[3] * inv};
    float4 o1 = {acc[4] * inv, acc[5] * inv, acc[6] * inv, acc[7] * inv};
    *(float4*)(dst)     = o0;
    *(float4*)(dst + 4) = o1;
  } else if (j == 1) {
    float4 o2 = {acc[8] * inv, acc[9] * inv, acc[10] * inv, acc[11] * inv};
    float4 o3 = {acc[12] * inv, acc[13] * inv, acc[14] * inv, acc[15] * inv};
    *(float4*)(dst + 8)  = o2;
    *(float4*)(dst + 12) = o3;
  }
}

// ---------------- fused MLP: relu([h_query|Agg]@W1^T+b1) @ W2^T + b2 + resid -> LayerNorm -------
__global__ __launch_bounds__(256) void mlp_kernel(
    const float* __restrict__ h_query, const float* __restrict__ Agg,
    const unsigned short* __restrict__ W1p, const unsigned short* __restrict__ W2p,
    const float* __restrict__ b1, const float* __restrict__ b2,
    const float* __restrict__ gamma, const float* __restrict__ beta,
    float* __restrict__ out) {
  constexpr int M = N_QUERY;
  constexpr int STRIDE = 136;               // ushorts per LDS row (272 B)
  __shared__ unsigned short hid[64 * STRIDE];

  const int l    = threadIdx.x & 63;
  const int w    = threadIdx.x >> 6;
  const int quad = l >> 4;
  const int col0 = l & 15;
  const int row0 = blockIdx.x * 64 + w * 16;
  int arow = row0 + col0;
  if (arow >= M) arow = M - 1;

  floatx4 acc[8];
#pragma unroll
  for (int i = 0; i < 8; i++) acc[i] = (floatx4){0.f, 0.f, 0.f, 0.f};
#pragma unroll
  for (int k0 = 0; k0 < 256; k0 += 32) {
    const float* sp = (k0 < 128) ? (h_query + (size_t)arow * 128 + k0)
                                 : (Agg + (size_t)arow * 128 + (k0 - 128));
    floatx4 a0 = *(const floatx4*)(sp + quad * 8);
    floatx4 a1 = *(const floatx4*)(sp + quad * 8 + 4);
    short8 af;
    af[0] = (short)f2bf_bits(a0[0]); af[1] = (short)f2bf_bits(a0[1]);
    af[2] = (short)f2bf_bits(a0[2]); af[3] = (short)f2bf_bits(a0[3]);
    af[4] = (short)f2bf_bits(a1[0]); af[5] = (short)f2bf_bits(a1[1]);
    af[6] = (short)f2bf_bits(a1[2]); af[7] = (short)f2bf_bits(a1[3]);
    const unsigned short* bbase = W1p + (size_t)(k0 >> 5) * 8 * 512 + l * 8;
#pragma unroll
    for (int nt = 0; nt < 8; nt++) {
      short8 bf = *(const short8*)(bbase + nt * 512);
      acc[nt] = __builtin_amdgcn_mfma_f32_16x16x32_bf16(af, bf, acc[nt], 0, 0, 0);
    }
  }
#pragma unroll
  for (int nt = 0; nt < 8; nt++) {
#pragma unroll
    for (int r = 0; r < 4; r++) {
      int rl = w * 16 + quad * 4 + r;
      float v = acc[nt][r] + b1[nt * 16 + col0];
      hid[rl * STRIDE + nt * 16 + col0] = f2bf_bits(fmaxf(v, 0.f));
    }
  }
  __syncthreads();

  floatx4 acc2[8];
#pragma unroll
  for (int i = 0; i < 8; i++) acc2[i] = (floatx4){0.f, 0.f, 0.f, 0.f};
  const int rloc = w * 16 + col0;
#pragma unroll
  for (int k0 = 0; k0 < 128; k0 += 32) {
    short8 af = *(const short8*)(hid + rloc * STRIDE + k0 + quad * 8);
    const unsigned short* bbase = W2p + (size_t)(k0 >> 5) * 8 * 512 + l * 8;
#pragma unroll
    for (int nt = 0; nt < 8; nt++) {
      short8 bf = *(const short8*)(bbase + nt * 512);
      acc2[nt] = __builtin_amdgcn_mfma_f32_16x16x32_bf16(af, bf, acc2[nt], 0, 0, 0);
    }
  }

#pragma unroll
  for (int r = 0; r < 4; r++) {
    int row = row0 + quad * 4 + r;
    int rr  = row < M ? row : M - 1;
    float v[8];
    float s1 = 0.f, s2 = 0.f;
#pragma unroll
    for (int nt = 0; nt < 8; nt++) {
      int c = nt * 16 + col0;
      v[nt] = acc2[nt][r] + b2[c] + h_query[(size_t)rr * 128 + c];
      s1 += v[nt];
    }
    s1 += __shfl_xor(s1, 1, 64); s1 += __shfl_xor(s1, 2, 64);
    s1 += __shfl_xor(s1, 4, 64); s1 += __shfl_xor(s1, 8, 64);
#pragma unroll
    for (int nt = 0; nt < 8; nt++) s2 += v[nt] * v[nt];
    s2 += __shfl_xor(s2, 1, 64); s2 += __shfl_xor(s2, 2, 64);
    s2 += __shfl_xor(s2, 4, 64); s2 += __shfl_xor(s2, 8, 64);
    float mean = s1 * (1.0f / 128.0f);
    float var  = s2 * (1.0f / 128.0f) - mean * mean;
    float rstd = rsqrtf(var + 1e-5f);
    if (row < M) {
#pragma unroll
      for (int nt = 0; nt < 8; nt++) {
        int c = nt * 16 + col0;
        out[(size_t)row * 128 + c] = (v[nt] - mean) * rstd * gamma[c] + beta[c];
      }
    }
  }
}

extern "C" void kernel_launch(void* const* d_in, const int* in_sizes, int n_in,
                              void* d_out, int out_size, void* d_ws, size_t ws_size,
                              hipStream_t stream) {
  const float* h_atom    = (const float*)d_in[0];
  const float* h_query   = (const float*)d_in[1];
  const float* edge_attr = (const float*)d_in[2];
  const float* W_q  = (const float*)d_in[3];
  const float* W_k  = (const float*)d_in[4];
  const float* W_v  = (const float*)d_in[5];
  const float* Wrbf = (const float*)d_in[6];
  const float* W1   = (const float*)d_in[7];
  const float* b1   = (const float*)d_in[8];
  const float* W2   = (const float*)d_in[9];
  const float* b2   = (const float*)d_in[10];
  const float* ln_g = (const float*)d_in[11];
  const float* ln_b = (const float*)d_in[12];
  const int* edge_index = (const int*)d_in[13];   // [0..E) = src
  float* out = (float*)d_out;

  char* ws = (char*)d_ws;
  unsigned char*  Kp8 = (unsigned char*)(ws);                  // 100000*128 B = 12.8 MB
  unsigned char*  Vp8 = (unsigned char*)(ws + 12800000);       // 100000*128 B = 12.8 MB
  unsigned short* Qb  = (unsigned short*)(ws + 25600000);      // 20000*128 bf16 = 5.12 MB
  float* Agg          = (float*)(ws + 30720000);               // 20000*128 f32  = 10.24 MB
  unsigned short* WKVp = (unsigned short*)(ws + 40960000);     // 128x256
  unsigned short* WQp  = WKVp + 32768;                         // 128x128
  unsigned short* W1p  = WQp  + 16384;                         // 256x128
  unsigned short* W2p  = W1p  + 32768;                         // 128x128

  pack_all_kernel<<<(98304 + 255) / 256, 256, 0, stream>>>(
      W_q, W_k, W_v, W1, W2, WKVp, WQp, W1p, W2p);

  // merged: K(fp8)/V(fp8) = h_atom @ [W_k|W_v]^T  and  Q(bf16) = h_query @ (W_q/4)^T
  constexpr int KB = (N_ATOM + 63) / 64;
  constexpr int QB = (N_QUERY + 63) / 64;
  gemm_kvq<<<KB + QB, 256, 0, stream>>>(h_atom, h_query, WKVp, WQp, Kp8, Vp8, Qb);

  // attention -> Agg
  attn_kernel<<<N_QUERY / 4, 256, 0, stream>>>(Qb, Kp8, Vp8, edge_attr, Wrbf, edge_index, Agg);

  // fused MLP + residual + LayerNorm -> out
  mlp_kernel<<<(N_QUERY + 63) / 64, 256, 0, stream>>>(
      h_query, Agg, W1p, W2p, b1, b2, ln_g, ln_b, out);
}